// Round 18
// baseline (205.931 us; speedup 1.0000x reference)
//
#include <hip/hip_runtime.h>

#define TT 128

// LIF constants
#define DECAY_U 0.75f
#define DECAY_V 0.96875f
#define THETA   5120.0f
#define POOLW   88.0f

__device__ __forceinline__ void lif_step(float xt, float& u, float& v, int& refc, float& s) {
    u = __fadd_rn(__fmul_rn(u, DECAY_U), __fmul_rn(xt, 64.0f));
    float vn = __fadd_rn(__fmul_rn(v, DECAY_V), u);
    v = refc ? 0.0f : vn;
    s = (v >= THETA) ? 1.0f : 0.0f;
    if (s > 0.f) { refc = 1; v = 0.f; }
    else         { refc = refc > 0 ? refc - 1 : 0; }
}

// Serial LIF over an LDS column: col[t*stride], t=0..127.
__device__ __forceinline__ void lif_seq_lds(float* col, int stride) {
    float u = 0.f, v = 0.f;
    int refc = 0;
    #pragma unroll 16
    for (int t = 0; t < TT; ++t) {
        float s;
        lif_step(col[t * stride], u, v, refc, s);
        col[t * stride] = s;
    }
}

// ---------------- LUT build ----------------
// LUT1[ky][idx10][oc16]: sum over set bits j (j = kx*2+c, ascending) of w1[oc][c][ky][kx]
// LUT2[tap*2+half][idx8][oc32]: sum over set bits j (c = half*8+j, ascending) of w2[oc][c][tap]
__global__ void lut_build_k(const float* __restrict__ w1, const float* __restrict__ w2,
                            float* __restrict__ LUT1, float* __restrict__ LUT2) {
    int id = blockIdx.x * 256 + threadIdx.x;
    if (id < 81920) {
        int ky = id >> 14;
        int idx = (id >> 4) & 1023;
        int oc = id & 15;
        float s = 0.f;
        #pragma unroll
        for (int j = 0; j < 10; ++j)
            if ((idx >> j) & 1) {
                int kx = j >> 1, c = j & 1;
                s += w1[oc*50 + c*25 + ky*5 + kx];
            }
        LUT1[id] = s;
    }
    if (id < 147456) {
        int th = id >> 13;            // tap*2+half
        int idx = (id >> 5) & 255;
        int oc = id & 31;
        int tap = th >> 1, half = th & 1;
        float s = 0.f;
        #pragma unroll
        for (int j = 0; j < 8; ++j)
            if ((idx >> j) & 1)
                s += w2[oc*144 + (half*8 + j)*9 + tap];
        LUT2[id] = s;
    }
}

// ---------------- L1: sum_pool(x,4)*88 + LIF + pack -> pk1 u8 ----------------
__global__ void pool1_lif_k(const float* __restrict__ x, unsigned char* __restrict__ pk1) {
    __shared__ float sb[TT][3];
    int t = threadIdx.x & 127, c = threadIdx.x >> 7;
    int pos = blockIdx.x & 1023, b = blockIdx.x >> 10;
    int px = pos & 31, py = pos >> 5;
    const float* base = x + (size_t)((((b*2 + c)*128 + py*4)*128) + px*4) * 128 + t;
    float s = 0.f;
    #pragma unroll
    for (int dy = 0; dy < 4; ++dy)
        #pragma unroll
        for (int dx = 0; dx < 4; ++dx)
            s += base[(dy*128 + dx) * 128];
    sb[t][c] = s * POOLW;
    __syncthreads();
    if (threadIdx.x < 2) lif_seq_lds(&sb[0][threadIdx.x], 3);
    __syncthreads();
    if (threadIdx.x < 128) {
        unsigned int v = (sb[t][0] > 0.5f ? 1u : 0u) | (sb[t][1] > 0.5f ? 2u : 0u);
        pk1[(size_t)b * 131072 + (size_t)pos * 128 + t] = (unsigned char)v;
    }
}

// ---------------- L2: conv1 via LUT (1 pos/block, 128 thr = t) + LIF + pack -------
__global__ __launch_bounds__(128) void conv1_lut_k(const unsigned char* __restrict__ pk1,
                                                   const float* __restrict__ LUT1,
                                                   unsigned short* __restrict__ pk2) {
    __shared__ float sb[TT*17];
    int t = threadIdx.x;
    int pos = blockIdx.x & 1023, b = blockIdx.x >> 10;
    int px = pos & 31, py = pos >> 5;
    const unsigned char* pp = pk1 + (size_t)b * 131072;

    unsigned int idx[5];
    #pragma unroll
    for (int ky = 0; ky < 5; ++ky) {
        int iy = py + ky - 2;
        unsigned int v = 0;
        #pragma unroll
        for (int kx = 0; kx < 5; ++kx) {
            int ix = px + kx - 2;
            bool vs = ((unsigned)iy < 32u) && ((unsigned)ix < 32u) && (t > 0);
            unsigned int nb = vs ? (unsigned int)pp[(iy*32 + ix)*128 + t - 1] : 0u;
            v |= nb << (kx*2);
        }
        idx[ky] = v;
    }

    float acc[16];
    #pragma unroll
    for (int k = 0; k < 16; ++k) acc[k] = 0.f;
    #pragma unroll
    for (int ky = 0; ky < 5; ++ky) {
        const float4* Lp = (const float4*)(LUT1 + (size_t)(ky*1024 + idx[ky]) * 16);
        #pragma unroll
        for (int q = 0; q < 4; ++q) {
            float4 l = Lp[q];
            acc[q*4+0] += l.x;
            acc[q*4+1] += l.y;
            acc[q*4+2] += l.z;
            acc[q*4+3] += l.w;
        }
    }

    #pragma unroll
    for (int oc = 0; oc < 16; ++oc) sb[t*17 + oc] = acc[oc];
    __syncthreads();
    if (t < 16) lif_seq_lds(&sb[t], 17);
    __syncthreads();
    {
        unsigned int w = 0;
        #pragma unroll
        for (int oc = 0; oc < 16; ++oc)
            w |= (sb[t*17 + oc] > 0.5f ? 1u : 0u) << oc;
        pk2[(size_t)b * 131072 + (size_t)pos * 128 + t] = (unsigned short)w;
    }
}

// ---------------- L3: sum_pool(2)*88 (delayed, packed in) + LIF + pack -> pk3 -----
__global__ __launch_bounds__(256) void pool2pack_k(const unsigned short* __restrict__ pk2,
                                                   unsigned short* __restrict__ pk3) {
    __shared__ float sb[TT][17];
    int tid = threadIdx.x;
    int t = tid & 127, half = tid >> 7;
    int pos = blockIdx.x & 255, b = blockIdx.x >> 8;
    int px = pos & 15, py = pos >> 4;
    unsigned int w0 = 0, w1 = 0, w2 = 0, w3 = 0;
    if (t > 0) {
        const unsigned short* q = pk2 + (size_t)b * 131072 + (size_t)(py*2*32 + px*2) * 128 + (t - 1);
        w0 = q[0]; w1 = q[128]; w2 = q[32*128]; w3 = q[33*128];
    }
    #pragma unroll
    for (int j = 0; j < 8; ++j) {
        int c = half*8 + j;
        int cnt = ((w0 >> c) & 1) + ((w1 >> c) & 1) + ((w2 >> c) & 1) + ((w3 >> c) & 1);
        sb[t][c] = POOLW * (float)cnt;
    }
    __syncthreads();
    if (tid < 16) lif_seq_lds(&sb[0][tid], 17);
    __syncthreads();
    if (tid < 128) {
        unsigned int w = 0;
        #pragma unroll
        for (int c = 0; c < 16; ++c)
            w |= (sb[tid][c] > 0.5f ? 1u : 0u) << c;
        pk3[(size_t)b * 32768 + (size_t)pos * 128 + tid] = (unsigned short)w;
    }
}

// ---------------- L4: conv2 via LUT (1 pos/block, 128 thr = t) + LIF + pack -------
__global__ __launch_bounds__(128) void conv2_lut_k(const unsigned short* __restrict__ pk3,
                                                   const float* __restrict__ LUT2,
                                                   unsigned int* __restrict__ pk4) {
    __shared__ float sb[TT*33];
    int t = threadIdx.x;
    int pos = blockIdx.x & 255, b = blockIdx.x >> 8;
    int px = pos & 15, py = pos >> 4;
    const unsigned short* pp = pk3 + (size_t)b * 32768;

    unsigned int wv[9];
    #pragma unroll
    for (int tap = 0; tap < 9; ++tap) {
        int ky = tap / 3, kx = tap - ky*3;
        int iy = py + ky - 1, ix = px + kx - 1;
        bool vs = ((unsigned)iy < 16u) && ((unsigned)ix < 16u) && (t > 0);
        wv[tap] = vs ? (unsigned int)pp[(iy*16 + ix)*128 + t - 1] : 0u;
    }

    float acc[32];
    #pragma unroll
    for (int k = 0; k < 32; ++k) acc[k] = 0.f;
    #pragma unroll
    for (int tap = 0; tap < 9; ++tap) {
        const float4* p0 = (const float4*)(LUT2 + (size_t)((tap*2 + 0)*256 + (wv[tap] & 255u)) * 32);
        #pragma unroll
        for (int q = 0; q < 8; ++q) {
            float4 l = p0[q];
            acc[q*4+0] += l.x;
            acc[q*4+1] += l.y;
            acc[q*4+2] += l.z;
            acc[q*4+3] += l.w;
        }
        const float4* p1 = (const float4*)(LUT2 + (size_t)((tap*2 + 1)*256 + ((wv[tap] >> 8) & 255u)) * 32);
        #pragma unroll
        for (int q = 0; q < 8; ++q) {
            float4 l = p1[q];
            acc[q*4+0] += l.x;
            acc[q*4+1] += l.y;
            acc[q*4+2] += l.z;
            acc[q*4+3] += l.w;
        }
    }

    #pragma unroll
    for (int oc = 0; oc < 32; ++oc) sb[t*33 + oc] = acc[oc];
    __syncthreads();
    if (t < 32) lif_seq_lds(&sb[t], 33);
    __syncthreads();
    {
        unsigned int w = 0;
        #pragma unroll
        for (int oc = 0; oc < 32; ++oc)
            w |= (sb[t*33 + oc] > 0.5f ? 1u : 0u) << oc;
        pk4[(size_t)b * 32768 + (size_t)pos * 128 + t] = w;
    }
}

// ---------------- L5: sum_pool(2)*88 (delayed, packed in) + LIF -> s5 fp32 --------
__global__ void pool3_lif_k(const unsigned int* __restrict__ pk4, float* __restrict__ s5) {
    __shared__ float sb[TT][3];
    int t = threadIdx.x & 127, pos = threadIdx.x >> 7;
    int n = blockIdx.x * 2 + pos;
    int px = n & 7, py = (n >> 3) & 7, c = (n >> 6) & 31, b = n >> 11;
    float acc = 0.f;
    if (t > 0) {
        const unsigned int* q = pk4 + (size_t)b * 32768 + (size_t)(py*2*16 + px*2) * 128 + (t - 1);
        unsigned int w0 = q[0], w1 = q[128], w2 = q[16*128], w3 = q[17*128];
        int cnt = ((w0 >> c) & 1) + ((w1 >> c) & 1) + ((w2 >> c) & 1) + ((w3 >> c) & 1);
        acc = POOLW * (float)cnt;
    }
    sb[t][pos] = acc;
    __syncthreads();
    if (threadIdx.x < 2) lif_seq_lds(&sb[0][threadIdx.x], 3);
    __syncthreads();
    s5[(size_t)n * TT + t] = sb[t][pos];
}

// ---------------- L6: fc1 tiled K-split GEMM ----------------
__global__ __launch_bounds__(256) void fc1_gemm_k(const float* __restrict__ s5,
                                                  const float* __restrict__ wf1,
                                                  float* __restrict__ part) {
    __shared__ float WT[64][68];
    __shared__ float ST[64][68];
    int bid = blockIdx.x;
    int kc = bid & 7;
    int ot = (bid >> 3) & 7;
    int tt = (bid >> 6) & 1;
    int b  = bid >> 7;
    int tid = threadIdx.x;
    int oo = tid >> 4;
    int to = tid & 15;

    const float* wbase = wf1 + (size_t)(ot*64) * 2048 + kc*256;
    const float* sbase = s5 + (size_t)b * 262144 + (size_t)(kc*256) * 128;

    float acc[4][4];
    #pragma unroll
    for (int i = 0; i < 4; ++i)
        #pragma unroll
        for (int j = 0; j < 4; ++j) acc[i][j] = 0.f;

    for (int ks = 0; ks < 4; ++ks) {
        __syncthreads();
        #pragma unroll
        for (int i = 0; i < 16; ++i) {
            int e = tid + 256*i;
            int o = e >> 6, f = e & 63;
            WT[f][o] = wbase[(size_t)o * 2048 + ks*64 + f];
        }
        #pragma unroll
        for (int i = 0; i < 16; ++i) {
            int e = tid + 256*i;
            int f = e >> 6, tl = e & 63;
            int tsrc = tt*64 + tl - 1;
            ST[f][tl] = (tsrc < 0) ? 0.f : sbase[(size_t)f * 128 + ks*64*128 + tsrc];
        }
        __syncthreads();
        #pragma unroll 4
        for (int k = 0; k < 64; ++k) {
            float4 a = *(const float4*)&WT[k][oo*4];
            float4 s = *(const float4*)&ST[k][to*4];
            acc[0][0] = fmaf(a.x, s.x, acc[0][0]);
            acc[0][1] = fmaf(a.x, s.y, acc[0][1]);
            acc[0][2] = fmaf(a.x, s.z, acc[0][2]);
            acc[0][3] = fmaf(a.x, s.w, acc[0][3]);
            acc[1][0] = fmaf(a.y, s.x, acc[1][0]);
            acc[1][1] = fmaf(a.y, s.y, acc[1][1]);
            acc[1][2] = fmaf(a.y, s.z, acc[1][2]);
            acc[1][3] = fmaf(a.y, s.w, acc[1][3]);
            acc[2][0] = fmaf(a.z, s.x, acc[2][0]);
            acc[2][1] = fmaf(a.z, s.y, acc[2][1]);
            acc[2][2] = fmaf(a.z, s.z, acc[2][2]);
            acc[2][3] = fmaf(a.z, s.w, acc[2][3]);
            acc[3][0] = fmaf(a.w, s.x, acc[3][0]);
            acc[3][1] = fmaf(a.w, s.y, acc[3][1]);
            acc[3][2] = fmaf(a.w, s.z, acc[3][2]);
            acc[3][3] = fmaf(a.w, s.w, acc[3][3]);
        }
    }
    float* pb = part + (size_t)kc * 524288 + (size_t)b * 65536
              + (size_t)(ot*64 + oo*4) * 128 + tt*64 + to*4;
    #pragma unroll
    for (int i = 0; i < 4; ++i)
        #pragma unroll
        for (int j = 0; j < 4; ++j)
            pb[(size_t)i * 128 + j] = acc[i][j];
}

// ---------------- L6b: sum 8 K-chunks (fixed order) + LIF -> s6 ----------------
__global__ void fc1_reduce_lif_k(const float* __restrict__ part, float* __restrict__ s6) {
    __shared__ float sb[TT][3];
    int t = threadIdx.x & 127, pos = threadIdx.x >> 7;
    int n = blockIdx.x * 2 + pos;
    float s = 0.f;
    #pragma unroll
    for (int kc = 0; kc < 8; ++kc)
        s += part[(size_t)kc * 524288 + (size_t)n * 128 + t];
    sb[t][pos] = s;
    __syncthreads();
    if (threadIdx.x < 2) lif_seq_lds(&sb[0][threadIdx.x], 3);
    __syncthreads();
    s6[(size_t)n * TT + t] = sb[t][pos];
}

// ---------------- L7: fc2 512->11 (delayed) + LIF + final shift -> out ----------
__global__ void fc2_lif_k(const float* __restrict__ s6, const float* __restrict__ wf2,
                          float* __restrict__ out) {
    __shared__ float sb[TT];
    int t = threadIdx.x;
    int o = blockIdx.x % 11, b = blockIdx.x / 11;
    float acc = 0.f;
    if (t > 0) {
        const float* sp = s6 + (size_t)b * 65536 + (t - 1);
        const float* wp = wf2 + o * 512;
        for (int f = 0; f < 512; f += 4) {
            float4 w = *(const float4*)&wp[f];
            acc = fmaf(w.x, sp[(size_t)f * 128], acc);
            acc = fmaf(w.y, sp[(size_t)(f+1) * 128], acc);
            acc = fmaf(w.z, sp[(size_t)(f+2) * 128], acc);
            acc = fmaf(w.w, sp[(size_t)(f+3) * 128], acc);
        }
    }
    sb[t] = acc;
    __syncthreads();
    if (t == 0) lif_seq_lds(sb, 1);
    __syncthreads();
    float* q = out + (size_t)(b*11 + o) * TT;
    if (t == 0) q[0] = 0.f;
    if (t < TT - 1) q[t + 1] = sb[t];
}

extern "C" void kernel_launch(void* const* d_in, const int* in_sizes, int n_in,
                              void* d_out, int out_size, void* d_ws, size_t ws_size,
                              hipStream_t stream) {
    const float* x   = (const float*)d_in[0];
    const float* w1  = (const float*)d_in[1];
    const float* w2  = (const float*)d_in[2];
    const float* wf1 = (const float*)d_in[3];
    const float* wf2 = (const float*)d_in[4];
    float* out = (float*)d_out;

    float* ws = (float*)d_ws;
    float* PART = ws;                        // 4,194,304 floats
    float* A    = PART + 4194304;            // 2,097,152 floats (s5)
    float* S6   = A + 2097152;               // 524,288 floats
    float* LUT1 = S6 + 524288;               // 81,920 floats
    float* LUT2 = LUT1 + 81920;              // 147,456 floats
    unsigned char*  PK1 = (unsigned char*)(LUT2 + 147456);         // 1,048,576 B
    unsigned short* PK2 = (unsigned short*)(PK1 + 1048576);        // 1,048,576 u16
    unsigned short* PK3 = (unsigned short*)((char*)PK2 + 2097152); // 262,144 u16
    unsigned int*   PK4 = (unsigned int*)((char*)PK3 + 524288);    // 262,144 u32

    // build conv LUTs
    lut_build_k<<<dim3(576), 256, 0, stream>>>(w1, w2, LUT1, LUT2);
    // L1: pool1+LIF+pack -> PK1
    pool1_lif_k<<<dim3(8192), 256, 0, stream>>>(x, PK1);
    // L2: conv1 LUT +LIF+pack -> PK2
    conv1_lut_k<<<dim3(8192), 128, 0, stream>>>(PK1, LUT1, PK2);
    // L3: pool2+LIF+pack -> PK3
    pool2pack_k<<<dim3(2048), 256, 0, stream>>>(PK2, PK3);
    // L4: conv2 LUT +LIF+pack -> PK4
    conv2_lut_k<<<dim3(2048), 128, 0, stream>>>(PK3, LUT2, PK4);
    // L5: pool3+LIF -> A (s5)
    pool3_lif_k<<<dim3(8192), 256, 0, stream>>>(PK4, A);
    // L6: fc1 GEMM -> PART; reduce+LIF -> S6
    fc1_gemm_k      <<<dim3(1024), 256, 0, stream>>>(A, wf1, PART);
    fc1_reduce_lif_k<<<dim3(2048), 256, 0, stream>>>(PART, S6);
    // L7: fc2+LIF+shift -> d_out
    fc2_lif_k<<<dim3(88), 128, 0, stream>>>(S6, wf2, out);
}

// Round 19
// 198.941 us; speedup vs baseline: 1.0351x; 1.0351x over previous
//
#include <hip/hip_runtime.h>

#define TT 128

// LIF constants
#define DECAY_U 0.75f
#define DECAY_V 0.96875f
#define THETA   5120.0f
#define POOLW   88.0f

__device__ __forceinline__ void lif_step(float xt, float& u, float& v, int& refc, float& s) {
    u = __fadd_rn(__fmul_rn(u, DECAY_U), __fmul_rn(xt, 64.0f));
    float vn = __fadd_rn(__fmul_rn(v, DECAY_V), u);
    v = refc ? 0.0f : vn;
    s = (v >= THETA) ? 1.0f : 0.0f;
    if (s > 0.f) { refc = 1; v = 0.f; }
    else         { refc = refc > 0 ? refc - 1 : 0; }
}

// Serial LIF over an LDS column: col[t*stride], t=0..127.
__device__ __forceinline__ void lif_seq_lds(float* col, int stride) {
    float u = 0.f, v = 0.f;
    int refc = 0;
    #pragma unroll 16
    for (int t = 0; t < TT; ++t) {
        float s;
        lif_step(col[t * stride], u, v, refc, s);
        col[t * stride] = s;
    }
}

// ---------------- LUT build ----------------
// LUT1[ky][idx10][oc16]: sum over set bits j (j = kx*2+c, ascending) of w1[oc][c][ky][kx]
// LUT2[tap*2+half][idx8][oc32]: sum over set bits j (c = half*8+j, ascending) of w2[oc][c][tap]
__global__ void lut_build_k(const float* __restrict__ w1, const float* __restrict__ w2,
                            float* __restrict__ LUT1, float* __restrict__ LUT2) {
    int id = blockIdx.x * 256 + threadIdx.x;
    if (id < 81920) {
        int ky = id >> 14;
        int idx = (id >> 4) & 1023;
        int oc = id & 15;
        float s = 0.f;
        #pragma unroll
        for (int j = 0; j < 10; ++j)
            if ((idx >> j) & 1) {
                int kx = j >> 1, c = j & 1;
                s += w1[oc*50 + c*25 + ky*5 + kx];
            }
        LUT1[id] = s;
    }
    if (id < 147456) {
        int th = id >> 13;            // tap*2+half
        int idx = (id >> 5) & 255;
        int oc = id & 31;
        int tap = th >> 1, half = th & 1;
        float s = 0.f;
        #pragma unroll
        for (int j = 0; j < 8; ++j)
            if ((idx >> j) & 1)
                s += w2[oc*144 + (half*8 + j)*9 + tap];
        LUT2[id] = s;
    }
}

// ---------------- L1: sum_pool(x,4)*88 + LIF + pack -> pk1 u8 ----------------
__global__ void pool1_lif_k(const float* __restrict__ x, unsigned char* __restrict__ pk1) {
    __shared__ float sb[TT][3];
    int t = threadIdx.x & 127, c = threadIdx.x >> 7;
    int pos = blockIdx.x & 1023, b = blockIdx.x >> 10;
    int px = pos & 31, py = pos >> 5;
    const float* base = x + (size_t)((((b*2 + c)*128 + py*4)*128) + px*4) * 128 + t;
    float s = 0.f;
    #pragma unroll
    for (int dy = 0; dy < 4; ++dy)
        #pragma unroll
        for (int dx = 0; dx < 4; ++dx)
            s += base[(dy*128 + dx) * 128];
    sb[t][c] = s * POOLW;
    __syncthreads();
    if (threadIdx.x < 2) lif_seq_lds(&sb[0][threadIdx.x], 3);
    __syncthreads();
    if (threadIdx.x < 128) {
        unsigned int v = (sb[t][0] > 0.5f ? 1u : 0u) | (sb[t][1] > 0.5f ? 2u : 0u);
        pk1[(size_t)b * 131072 + (size_t)pos * 128 + t] = (unsigned char)v;
    }
}

// ---------------- L2: conv1 via LUT, lane=oc coalesced (1 pos/block, 256 thr) -----
// thread = (oc 0..15, tg 0..15), 8 t each. LUT reads coalesced across oc lanes.
__global__ __launch_bounds__(256) void conv1_lut_k(const unsigned char* __restrict__ pk1,
                                                   const float* __restrict__ LUT1,
                                                   unsigned short* __restrict__ pk2) {
    __shared__ unsigned int XIDX[5*132];
    __shared__ float sb[TT*17];
    int tid = threadIdx.x;
    int pos = blockIdx.x & 1023, b = blockIdx.x >> 10;
    int px = pos & 31, py = pos >> 5;
    const unsigned char* pp = pk1 + (size_t)b * 131072;

    // stage per-(ky,t) 10-bit indices
    #pragma unroll
    for (int i = 0; i < 3; ++i) {
        int e = tid + 256*i;
        if (e < 640) {
            int ky = e >> 7, t = e & 127;
            int iy = py + ky - 2;
            unsigned int v = 0;
            #pragma unroll
            for (int kx = 0; kx < 5; ++kx) {
                int ix = px + kx - 2;
                bool vs = ((unsigned)iy < 32u) && ((unsigned)ix < 32u) && (t > 0);
                unsigned int nb = vs ? (unsigned int)pp[(iy*32 + ix)*128 + t - 1] : 0u;
                v |= nb << (kx*2);
            }
            XIDX[ky*132 + t] = v;
        }
    }
    __syncthreads();

    int oc = tid & 15, tg = tid >> 4;
    #pragma unroll
    for (int i = 0; i < 8; ++i) {
        int t = tg*8 + i;
        float acc = 0.f;
        #pragma unroll
        for (int ky = 0; ky < 5; ++ky)
            acc += LUT1[(size_t)(ky*1024 + XIDX[ky*132 + t]) * 16 + oc];
        sb[t*17 + oc] = acc;
    }
    __syncthreads();
    if (tid < 16) lif_seq_lds(&sb[tid], 17);
    __syncthreads();
    if (tid < 128) {
        int t = tid;
        unsigned int w = 0;
        #pragma unroll
        for (int o = 0; o < 16; ++o)
            w |= (sb[t*17 + o] > 0.5f ? 1u : 0u) << o;
        pk2[(size_t)b * 131072 + (size_t)pos * 128 + t] = (unsigned short)w;
    }
}

// ---------------- L3: sum_pool(2)*88 (delayed, packed in) + LIF + pack -> pk3 -----
__global__ __launch_bounds__(256) void pool2pack_k(const unsigned short* __restrict__ pk2,
                                                   unsigned short* __restrict__ pk3) {
    __shared__ float sb[TT][17];
    int tid = threadIdx.x;
    int t = tid & 127, half = tid >> 7;
    int pos = blockIdx.x & 255, b = blockIdx.x >> 8;
    int px = pos & 15, py = pos >> 4;
    unsigned int w0 = 0, w1 = 0, w2 = 0, w3 = 0;
    if (t > 0) {
        const unsigned short* q = pk2 + (size_t)b * 131072 + (size_t)(py*2*32 + px*2) * 128 + (t - 1);
        w0 = q[0]; w1 = q[128]; w2 = q[32*128]; w3 = q[33*128];
    }
    #pragma unroll
    for (int j = 0; j < 8; ++j) {
        int c = half*8 + j;
        int cnt = ((w0 >> c) & 1) + ((w1 >> c) & 1) + ((w2 >> c) & 1) + ((w3 >> c) & 1);
        sb[t][c] = POOLW * (float)cnt;
    }
    __syncthreads();
    if (tid < 16) lif_seq_lds(&sb[0][tid], 17);
    __syncthreads();
    if (tid < 128) {
        unsigned int w = 0;
        #pragma unroll
        for (int c = 0; c < 16; ++c)
            w |= (sb[tid][c] > 0.5f ? 1u : 0u) << c;
        pk3[(size_t)b * 32768 + (size_t)pos * 128 + tid] = (unsigned short)w;
    }
}

// ---------------- L4: conv2 via LUT, lane=oc coalesced (1 pos/block, 256 thr) -----
// thread = (oc 0..31, tg 0..7), 16 t each. LUT reads coalesced across oc lanes.
__global__ __launch_bounds__(256) void conv2_lut_k(const unsigned short* __restrict__ pk3,
                                                   const float* __restrict__ LUT2,
                                                   unsigned int* __restrict__ pk4) {
    __shared__ unsigned int XL[9*132];
    __shared__ float sb[TT*33];
    int tid = threadIdx.x;
    int pos = blockIdx.x & 255, b = blockIdx.x >> 8;
    int px = pos & 15, py = pos >> 4;
    const unsigned short* pp = pk3 + (size_t)b * 32768;

    // stage per-(tap,t) 16-bit patterns
    #pragma unroll
    for (int i = 0; i < 5; ++i) {
        int e = tid + 256*i;
        if (e < 1152) {
            int tap = e >> 7, t = e & 127;
            int ky = tap / 3, kx = tap - ky*3;
            int iy = py + ky - 1, ix = px + kx - 1;
            bool vs = ((unsigned)iy < 16u) && ((unsigned)ix < 16u) && (t > 0);
            XL[tap*132 + t] = vs ? (unsigned int)pp[(iy*16 + ix)*128 + t - 1] : 0u;
        }
    }
    __syncthreads();

    int oc = tid & 31, tg = tid >> 5;
    #pragma unroll 1
    for (int i = 0; i < 16; ++i) {
        int t = tg*16 + i;
        float acc = 0.f;
        #pragma unroll
        for (int tap = 0; tap < 9; ++tap) {
            unsigned int w = XL[tap*132 + t];
            acc += LUT2[(size_t)((tap*2 + 0)*256 + (w & 255u)) * 32 + oc];
            acc += LUT2[(size_t)((tap*2 + 1)*256 + ((w >> 8) & 255u)) * 32 + oc];
        }
        sb[t*33 + oc] = acc;
    }
    __syncthreads();
    if (tid < 32) lif_seq_lds(&sb[tid], 33);
    __syncthreads();
    if (tid < 128) {
        int t = tid;
        unsigned int w = 0;
        #pragma unroll
        for (int o = 0; o < 32; ++o)
            w |= (sb[t*33 + o] > 0.5f ? 1u : 0u) << o;
        pk4[(size_t)b * 32768 + (size_t)pos * 128 + t] = w;
    }
}

// ---------------- L5: sum_pool(2)*88 (delayed, packed in) + LIF -> s5 fp32 --------
__global__ void pool3_lif_k(const unsigned int* __restrict__ pk4, float* __restrict__ s5) {
    __shared__ float sb[TT][3];
    int t = threadIdx.x & 127, pos = threadIdx.x >> 7;
    int n = blockIdx.x * 2 + pos;
    int px = n & 7, py = (n >> 3) & 7, c = (n >> 6) & 31, b = n >> 11;
    float acc = 0.f;
    if (t > 0) {
        const unsigned int* q = pk4 + (size_t)b * 32768 + (size_t)(py*2*16 + px*2) * 128 + (t - 1);
        unsigned int w0 = q[0], w1 = q[128], w2 = q[16*128], w3 = q[17*128];
        int cnt = ((w0 >> c) & 1) + ((w1 >> c) & 1) + ((w2 >> c) & 1) + ((w3 >> c) & 1);
        acc = POOLW * (float)cnt;
    }
    sb[t][pos] = acc;
    __syncthreads();
    if (threadIdx.x < 2) lif_seq_lds(&sb[0][threadIdx.x], 3);
    __syncthreads();
    s5[(size_t)n * TT + t] = sb[t][pos];
}

// ---------------- L6: fc1 tiled K-split GEMM ----------------
__global__ __launch_bounds__(256) void fc1_gemm_k(const float* __restrict__ s5,
                                                  const float* __restrict__ wf1,
                                                  float* __restrict__ part) {
    __shared__ float WT[64][68];
    __shared__ float ST[64][68];
    int bid = blockIdx.x;
    int kc = bid & 7;
    int ot = (bid >> 3) & 7;
    int tt = (bid >> 6) & 1;
    int b  = bid >> 7;
    int tid = threadIdx.x;
    int oo = tid >> 4;
    int to = tid & 15;

    const float* wbase = wf1 + (size_t)(ot*64) * 2048 + kc*256;
    const float* sbase = s5 + (size_t)b * 262144 + (size_t)(kc*256) * 128;

    float acc[4][4];
    #pragma unroll
    for (int i = 0; i < 4; ++i)
        #pragma unroll
        for (int j = 0; j < 4; ++j) acc[i][j] = 0.f;

    for (int ks = 0; ks < 4; ++ks) {
        __syncthreads();
        #pragma unroll
        for (int i = 0; i < 16; ++i) {
            int e = tid + 256*i;
            int o = e >> 6, f = e & 63;
            WT[f][o] = wbase[(size_t)o * 2048 + ks*64 + f];
        }
        #pragma unroll
        for (int i = 0; i < 16; ++i) {
            int e = tid + 256*i;
            int f = e >> 6, tl = e & 63;
            int tsrc = tt*64 + tl - 1;
            ST[f][tl] = (tsrc < 0) ? 0.f : sbase[(size_t)f * 128 + ks*64*128 + tsrc];
        }
        __syncthreads();
        #pragma unroll 4
        for (int k = 0; k < 64; ++k) {
            float4 a = *(const float4*)&WT[k][oo*4];
            float4 s = *(const float4*)&ST[k][to*4];
            acc[0][0] = fmaf(a.x, s.x, acc[0][0]);
            acc[0][1] = fmaf(a.x, s.y, acc[0][1]);
            acc[0][2] = fmaf(a.x, s.z, acc[0][2]);
            acc[0][3] = fmaf(a.x, s.w, acc[0][3]);
            acc[1][0] = fmaf(a.y, s.x, acc[1][0]);
            acc[1][1] = fmaf(a.y, s.y, acc[1][1]);
            acc[1][2] = fmaf(a.y, s.z, acc[1][2]);
            acc[1][3] = fmaf(a.y, s.w, acc[1][3]);
            acc[2][0] = fmaf(a.z, s.x, acc[2][0]);
            acc[2][1] = fmaf(a.z, s.y, acc[2][1]);
            acc[2][2] = fmaf(a.z, s.z, acc[2][2]);
            acc[2][3] = fmaf(a.z, s.w, acc[2][3]);
            acc[3][0] = fmaf(a.w, s.x, acc[3][0]);
            acc[3][1] = fmaf(a.w, s.y, acc[3][1]);
            acc[3][2] = fmaf(a.w, s.z, acc[3][2]);
            acc[3][3] = fmaf(a.w, s.w, acc[3][3]);
        }
    }
    float* pb = part + (size_t)kc * 524288 + (size_t)b * 65536
              + (size_t)(ot*64 + oo*4) * 128 + tt*64 + to*4;
    #pragma unroll
    for (int i = 0; i < 4; ++i)
        #pragma unroll
        for (int j = 0; j < 4; ++j)
            pb[(size_t)i * 128 + j] = acc[i][j];
}

// ---------------- L6b: sum 8 K-chunks (fixed order) + LIF -> s6 ----------------
__global__ void fc1_reduce_lif_k(const float* __restrict__ part, float* __restrict__ s6) {
    __shared__ float sb[TT][3];
    int t = threadIdx.x & 127, pos = threadIdx.x >> 7;
    int n = blockIdx.x * 2 + pos;
    float s = 0.f;
    #pragma unroll
    for (int kc = 0; kc < 8; ++kc)
        s += part[(size_t)kc * 524288 + (size_t)n * 128 + t];
    sb[t][pos] = s;
    __syncthreads();
    if (threadIdx.x < 2) lif_seq_lds(&sb[0][threadIdx.x], 3);
    __syncthreads();
    s6[(size_t)n * TT + t] = sb[t][pos];
}

// ---------------- L7: fc2 512->11 (delayed) + LIF + final shift -> out ----------
__global__ void fc2_lif_k(const float* __restrict__ s6, const float* __restrict__ wf2,
                          float* __restrict__ out) {
    __shared__ float sb[TT];
    int t = threadIdx.x;
    int o = blockIdx.x % 11, b = blockIdx.x / 11;
    float acc = 0.f;
    if (t > 0) {
        const float* sp = s6 + (size_t)b * 65536 + (t - 1);
        const float* wp = wf2 + o * 512;
        for (int f = 0; f < 512; f += 4) {
            float4 w = *(const float4*)&wp[f];
            acc = fmaf(w.x, sp[(size_t)f * 128], acc);
            acc = fmaf(w.y, sp[(size_t)(f+1) * 128], acc);
            acc = fmaf(w.z, sp[(size_t)(f+2) * 128], acc);
            acc = fmaf(w.w, sp[(size_t)(f+3) * 128], acc);
        }
    }
    sb[t] = acc;
    __syncthreads();
    if (t == 0) lif_seq_lds(sb, 1);
    __syncthreads();
    float* q = out + (size_t)(b*11 + o) * TT;
    if (t == 0) q[0] = 0.f;
    if (t < TT - 1) q[t + 1] = sb[t];
}

extern "C" void kernel_launch(void* const* d_in, const int* in_sizes, int n_in,
                              void* d_out, int out_size, void* d_ws, size_t ws_size,
                              hipStream_t stream) {
    const float* x   = (const float*)d_in[0];
    const float* w1  = (const float*)d_in[1];
    const float* w2  = (const float*)d_in[2];
    const float* wf1 = (const float*)d_in[3];
    const float* wf2 = (const float*)d_in[4];
    float* out = (float*)d_out;

    float* ws = (float*)d_ws;
    float* PART = ws;                        // 4,194,304 floats
    float* A    = PART + 4194304;            // 2,097,152 floats (s5)
    float* S6   = A + 2097152;               // 524,288 floats
    float* LUT1 = S6 + 524288;               // 81,920 floats
    float* LUT2 = LUT1 + 81920;              // 147,456 floats
    unsigned char*  PK1 = (unsigned char*)(LUT2 + 147456);         // 1,048,576 B
    unsigned short* PK2 = (unsigned short*)(PK1 + 1048576);        // 1,048,576 u16
    unsigned short* PK3 = (unsigned short*)((char*)PK2 + 2097152); // 262,144 u16
    unsigned int*   PK4 = (unsigned int*)((char*)PK3 + 524288);    // 262,144 u32

    // build conv LUTs
    lut_build_k<<<dim3(576), 256, 0, stream>>>(w1, w2, LUT1, LUT2);
    // L1: pool1+LIF+pack -> PK1
    pool1_lif_k<<<dim3(8192), 256, 0, stream>>>(x, PK1);
    // L2: conv1 LUT (lane=oc) +LIF+pack -> PK2
    conv1_lut_k<<<dim3(8192), 256, 0, stream>>>(PK1, LUT1, PK2);
    // L3: pool2+LIF+pack -> PK3
    pool2pack_k<<<dim3(2048), 256, 0, stream>>>(PK2, PK3);
    // L4: conv2 LUT (lane=oc) +LIF+pack -> PK4
    conv2_lut_k<<<dim3(2048), 256, 0, stream>>>(PK3, LUT2, PK4);
    // L5: pool3+LIF -> A (s5)
    pool3_lif_k<<<dim3(8192), 256, 0, stream>>>(PK4, A);
    // L6: fc1 GEMM -> PART; reduce+LIF -> S6
    fc1_gemm_k      <<<dim3(1024), 256, 0, stream>>>(A, wf1, PART);
    fc1_reduce_lif_k<<<dim3(2048), 256, 0, stream>>>(PART, S6);
    // L7: fc2+LIF+shift -> d_out
    fc2_lif_k<<<dim3(88), 128, 0, stream>>>(S6, wf2, out);
}